// Round 2
// baseline (232.510 us; speedup 1.0000x reference)
//
#include <hip/hip_runtime.h>

// Problem constants (HyperNetwork_9990093931021)
#define BB 256   // batch
#define CC 512   // channels
#define NZ 256   // flattened spatial (16*16)
#define ZD 64    // z_dim
#define KK 9     // out_c * f * f = 1*3*3

// ---- DPP cross-lane add helpers (VALU-only, no LDS pipe) ----
template<int CTRL>
__device__ __forceinline__ float dpp_add(float v) {
    int o = __builtin_amdgcn_update_dpp(0, __float_as_int(v), CTRL, 0xF, 0xF, true);
    return v + __int_as_float(o);
}
// sum over aligned 8-lane group
__device__ __forceinline__ float red8(float v) {
    v = dpp_add<0xB1>(v);   // quad_perm [1,0,3,2]  (xor 1)
    v = dpp_add<0x4E>(v);   // quad_perm [2,3,0,1]  (xor 2)
    v = dpp_add<0x141>(v);  // row_half_mirror      (combine quads of 8-lane half)
    return v;
}

// ============================================================================
// Kernel A: build fused weight WfT[c][k][n] = sum_z W_in[c,n,z]*W_out[z,k]
//           and fused bias bk[c][k] = b_in[c,:].W_out[:,k] + b_out[k]
// grid = C blocks x 512 threads. Reads W_in once (33.5 MB), writes 4.7 MB.
// ============================================================================
__global__ __launch_bounds__(512, 2)
void wf_kernel(const float* __restrict__ W_in,
               const float* __restrict__ b_in,
               const float* __restrict__ W_out,
               const float* __restrict__ b_out,
               float* __restrict__ wf,    // [C][KK][NZ]
               float* __restrict__ bk) {  // [C][KK]
    __shared__ __align__(16) float s_woutT[KK * ZD]; // W_out transposed, [k][z]
    __shared__ float s_bin[ZD];

    const int c = blockIdx.x;
    const int t = threadIdx.x;

    for (int i = t; i < KK * ZD; i += 512) {
        float v = W_out[i];
        int zz = i / KK, k = i - zz * KK;
        s_woutT[k * ZD + zz] = v;
    }
    if (t < ZD) s_bin[t] = b_in[c * ZD + t];
    __syncthreads();

    const int n = t >> 1, half = t & 1;            // 2 threads per n, 32 z each
    const float* wrow = W_in + ((size_t)c * NZ + n) * ZD + half * 32;
    float acc[KK];
#pragma unroll
    for (int k = 0; k < KK; ++k) acc[k] = 0.f;
#pragma unroll
    for (int j = 0; j < 8; ++j) {
        const float4 w = *reinterpret_cast<const float4*>(wrow + 4 * j);
#pragma unroll
        for (int k = 0; k < KK; ++k) {
            const float4 wo = *reinterpret_cast<const float4*>(
                &s_woutT[k * ZD + half * 32 + 4 * j]);
            acc[k] += w.x * wo.x + w.y * wo.y + w.z * wo.z + w.w * wo.w;
        }
    }
#pragma unroll
    for (int k = 0; k < KK; ++k) acc[k] = dpp_add<0xB1>(acc[k]); // half0+half1
    if (half == 0) {
#pragma unroll
        for (int k = 0; k < KK; ++k) wf[((size_t)c * KK + k) * NZ + n] = acc[k];
    }
    if (t < KK) { // fused bias
        float s = 0.f;
        for (int zz = 0; zz < ZD; ++zz) s += s_bin[zz] * s_woutT[t * ZD + zz];
        bk[c * KK + t] = s + b_out[t];
    }
}

// ============================================================================
// Kernel B: out[b,c,k] = z[b,c,:] . WfT[c][k][:] + bk[c][k]
// grid = (C, 2) x 256 threads (4 waves). Each block: one c, 128 batches.
// 1024 blocks -> 4 blocks/CU. Pure stream: z read once, WfT from L2/L3.
// 8-lane group owns 4 consecutive b; wave = 32 b; 4 waves = 128 b.
// Prefetch depth 2 (triple-buffered z registers).
// ============================================================================
__global__ __launch_bounds__(256, 2)
void out_kernel(const float* __restrict__ z,
                const float* __restrict__ wf,
                const float* __restrict__ bk,
                float* __restrict__ out) {
    __shared__ __align__(16) float s_wfT[KK * NZ];
    __shared__ float s_biask[KK];

    const int c = blockIdx.x;
    const int bh = blockIdx.y;          // batch half: 0 / 1
    const int t = threadIdx.x;

    // stage WfT[c] (9216 B) — fully coalesced float4 copy, ws is L2/L3-hot
    {
        const float4* src = reinterpret_cast<const float4*>(wf + (size_t)c * KK * NZ);
        float4* dst = reinterpret_cast<float4*>(s_wfT);
        for (int i = t; i < KK * NZ / 4; i += 256) dst[i] = src[i];
        if (t < KK) s_biask[t] = bk[c * KK + t];
    }
    __syncthreads();

    const int lane = t & 63;
    const int wave = t >> 6;             // 0..3
    const int g = lane >> 3;
    const int sub = lane & 7;            // lane's slice of the n dimension
    const int b0 = bh * 128 + wave * 32 + g * 4;
    const float biasS = s_biask[sub];
    const float bias8 = s_biask[8];

    const float* xp = z + ((size_t)b0 * CC + c) * NZ + sub * 4; // lane base
    const size_t bstr = (size_t)CC * NZ;                        // b stride (floats)

    float acc[4][KK];
#pragma unroll
    for (int bb = 0; bb < 4; ++bb)
#pragma unroll
        for (int k = 0; k < KK; ++k) acc[bb][k] = 0.f;

    // triple-buffered z stream: prefetch distance 2 (8 float4 in flight)
    float4 xb[3][4];
#pragma unroll
    for (int bb = 0; bb < 4; ++bb)
        xb[0][bb] = *reinterpret_cast<const float4*>(xp + bb * bstr);
#pragma unroll
    for (int bb = 0; bb < 4; ++bb)
        xb[1][bb] = *reinterpret_cast<const float4*>(xp + bb * bstr + 32);

#pragma unroll
    for (int j = 0; j < 8; ++j) {
        if (j < 6) {
#pragma unroll
            for (int bb = 0; bb < 4; ++bb)
                xb[(j + 2) % 3][bb] =
                    *reinterpret_cast<const float4*>(xp + bb * bstr + (j + 2) * 32);
        }
#pragma unroll
        for (int k = 0; k < KK; ++k) {
            const float4 wfv = *reinterpret_cast<const float4*>(
                &s_wfT[k * NZ + sub * 4 + j * 32]);   // 32 distinct banks, conflict-free
#pragma unroll
            for (int bb = 0; bb < 4; ++bb) {
                const float4 x = xb[j % 3][bb];
                acc[bb][k] += x.x * wfv.x + x.y * wfv.y + x.z * wfv.z + x.w * wfv.w;
            }
        }
    }

#pragma unroll
    for (int bb = 0; bb < 4; ++bb)
#pragma unroll
        for (int k = 0; k < KK; ++k) acc[bb][k] = red8(acc[bb][k]);

#pragma unroll
    for (int bb = 0; bb < 4; ++bb) {
        float v = acc[bb][0];
#pragma unroll
        for (int k = 1; k < 8; ++k) {
            if (sub == k) v = acc[bb][k];   // cndmask chain
        }
        const size_t o0 = ((size_t)(b0 + bb) * CC + c) * KK;
        out[o0 + sub] = v + biasS;
        if (sub == 0) out[o0 + 8] = acc[bb][8] + bias8;
    }
}

// ============================================================================
// Fallback: previous session's fused single kernel (harness-verified 228 µs),
// used only if the workspace is too small for the split path.
// ============================================================================
__global__ __launch_bounds__(512, 2)
void hyper_kernel(const float* __restrict__ z,
                  const float* __restrict__ W_in,
                  const float* __restrict__ b_in,
                  const float* __restrict__ W_out,
                  const float* __restrict__ b_out,
                  float* __restrict__ out) {
    __shared__ __align__(16) float s_wfT[KK * NZ];   // fused weight, [k][n]
    __shared__ __align__(16) float s_woutT[KK * ZD]; // W_out transposed, [k][z]
    __shared__ float s_bin[ZD];
    __shared__ float s_biask[KK];

    const int c = blockIdx.x;
    const int t = threadIdx.x;

    for (int i = t; i < KK * ZD; i += 512) {
        float v = W_out[i];
        int zz = i / KK, k = i - zz * KK;
        s_woutT[k * ZD + zz] = v;
    }
    if (t < ZD) s_bin[t] = b_in[c * ZD + t];
    __syncthreads();

    {
        const int n = t >> 1, half = t & 1;
        const float* wrow = W_in + ((size_t)c * NZ + n) * ZD + half * 32;
        float acc[KK];
#pragma unroll
        for (int k = 0; k < KK; ++k) acc[k] = 0.f;
#pragma unroll
        for (int j = 0; j < 8; ++j) {
            const float4 w = *reinterpret_cast<const float4*>(wrow + 4 * j);
#pragma unroll
            for (int k = 0; k < KK; ++k) {
                const float4 wo = *reinterpret_cast<const float4*>(
                    &s_woutT[k * ZD + half * 32 + 4 * j]);
                acc[k] += w.x * wo.x + w.y * wo.y + w.z * wo.z + w.w * wo.w;
            }
        }
#pragma unroll
        for (int k = 0; k < KK; ++k) acc[k] = dpp_add<0xB1>(acc[k]);
        if (half == 0) {
#pragma unroll
            for (int k = 0; k < KK; ++k) s_wfT[k * NZ + n] = acc[k];
        }
        if (t < KK) {
            float s = 0.f;
            for (int zz = 0; zz < ZD; ++zz) s += s_bin[zz] * s_woutT[t * ZD + zz];
            s_biask[t] = s + b_out[t];
        }
    }
    __syncthreads();

    const int lane = t & 63;
    const int wave = t >> 6;
    const int g = lane >> 3;
    const int sub = lane & 7;
    const int b0 = wave * 32 + g * 4;
    const float biasS = s_biask[sub];
    const float bias8 = s_biask[8];

    const float* xp = z + ((size_t)b0 * CC + c) * NZ + sub * 4;
    const size_t bstr = (size_t)CC * NZ;

    float acc[4][KK];
#pragma unroll
    for (int bb = 0; bb < 4; ++bb)
#pragma unroll
        for (int k = 0; k < KK; ++k) acc[bb][k] = 0.f;

    float4 xb[2][4];
#pragma unroll
    for (int bb = 0; bb < 4; ++bb)
        xb[0][bb] = *reinterpret_cast<const float4*>(xp + bb * bstr);

#pragma unroll
    for (int j = 0; j < 8; ++j) {
        if (j < 7) {
#pragma unroll
            for (int bb = 0; bb < 4; ++bb)
                xb[(j + 1) & 1][bb] =
                    *reinterpret_cast<const float4*>(xp + bb * bstr + (j + 1) * 32);
        }
#pragma unroll
        for (int k = 0; k < KK; ++k) {
            const float4 wfv = *reinterpret_cast<const float4*>(
                &s_wfT[k * NZ + sub * 4 + j * 32]);
#pragma unroll
            for (int bb = 0; bb < 4; ++bb) {
                const float4 x = xb[j & 1][bb];
                acc[bb][k] += x.x * wfv.x + x.y * wfv.y + x.z * wfv.z + x.w * wfv.w;
            }
        }
    }

#pragma unroll
    for (int bb = 0; bb < 4; ++bb)
#pragma unroll
        for (int k = 0; k < KK; ++k) acc[bb][k] = red8(acc[bb][k]);

#pragma unroll
    for (int bb = 0; bb < 4; ++bb) {
        float v = acc[bb][0];
#pragma unroll
        for (int k = 1; k < 8; ++k) {
            if (sub == k) v = acc[bb][k];
        }
        const size_t o0 = ((size_t)(b0 + bb) * CC + c) * KK;
        out[o0 + sub] = v + biasS;
        if (sub == 0) out[o0 + 8] = acc[bb][8] + bias8;
    }
}

extern "C" void kernel_launch(void* const* d_in, const int* in_sizes, int n_in,
                              void* d_out, int out_size, void* d_ws, size_t ws_size,
                              hipStream_t stream) {
    const float* z     = (const float*)d_in[0];
    const float* W_in  = (const float*)d_in[1];
    const float* b_in  = (const float*)d_in[2];
    const float* W_out = (const float*)d_in[3];
    const float* b_out = (const float*)d_in[4];
    float* out = (float*)d_out;

    const size_t WF_ELTS = (size_t)CC * KK * NZ;   // 1,179,648 floats (4.72 MB)
    const size_t BK_ELTS = (size_t)CC * KK;        // 4,608 floats
    const size_t NEED = (WF_ELTS + BK_ELTS) * sizeof(float);

    if (d_ws != nullptr && ws_size >= NEED) {
        float* wf = (float*)d_ws;
        float* bk = wf + WF_ELTS;
        wf_kernel<<<dim3(CC), dim3(512), 0, stream>>>(W_in, b_in, W_out, b_out, wf, bk);
        out_kernel<<<dim3(CC, 2), dim3(256), 0, stream>>>(z, wf, bk, out);
    } else {
        hyper_kernel<<<dim3(CC), dim3(512), 0, stream>>>(z, W_in, b_in, W_out, b_out, out);
    }
}